// Round 1
// baseline (7941.442 us; speedup 1.0000x reference)
//
#include <hip/hip_runtime.h>
#include <hip/hip_bf16.h>

// ---------------------------------------------------------------------------
// Mask2Former transformer decoder, fp32 reference-faithful implementation.
// L=9 layers, D=256, Q=100, NH=8 (hd=32), FF=2048, NC=151, B=8, HM=112.
// mems cycle 14x14 (K=196), 28x28 (784), 56x56 (3136).
// ---------------------------------------------------------------------------

#define LL 9
#define DD 256
#define QQ 100
#define NHH 8
#define HDD 32
#define FFD 2048
#define NCC 151
#define BB 8
#define HMM 112
#define PP (HMM*HMM)      // 12544
#define KMAX 3136

__global__ void initq_k(const float* __restrict__ qf, const float* __restrict__ qe,
                        float* __restrict__ q) {
  int idx = blockIdx.x * 256 + threadIdx.x;       // 800 blocks * 256 = 204800
  int qd = idx % (QQ * DD);
  q[idx] = qf[qd] + qe[qd];
}

// LayerNorm over D=256. grid = rows (800), block = 64 (one wave).
__global__ __launch_bounds__(64) void ln_k(const float* __restrict__ x,
                                           const float* __restrict__ g,
                                           const float* __restrict__ b,
                                           float* __restrict__ y) {
  int r = blockIdx.x, t = threadIdx.x;
  const float* xr = x + (size_t)r * DD;
  float* yr = y + (size_t)r * DD;
  float v[4];
  float s = 0.f, sq = 0.f;
#pragma unroll
  for (int i = 0; i < 4; i++) {
    v[i] = xr[t + 64 * i];
    s += v[i];
    sq += v[i] * v[i];
  }
#pragma unroll
  for (int o = 32; o > 0; o >>= 1) {
    s += __shfl_xor(s, o, 64);
    sq += __shfl_xor(sq, o, 64);
  }
  float mean = s * (1.f / DD);
  float var = sq * (1.f / DD) - mean * mean;
  float rs = rsqrtf(var + 1e-5f);
#pragma unroll
  for (int i = 0; i < 4; i++) {
    int c = t + 64 * i;
    yr[c] = g[c] * (v[i] - mean) * rs + b[c];
  }
}

// Row softmax in-place. grid = rows (6400), block 256. KL <= 3136.
__global__ __launch_bounds__(256) void softmax_k(float* __restrict__ s, int KL) {
  int row = blockIdx.x, t = threadIdx.x;
  float* sr = s + (size_t)row * KL;
  __shared__ float buf[KMAX];
  __shared__ float red[4];
  float lm = -3.402823466e38f;
  for (int k = t; k < KL; k += 256) {
    float v = sr[k];
    buf[k] = v;
    lm = fmaxf(lm, v);
  }
#pragma unroll
  for (int o = 32; o > 0; o >>= 1) lm = fmaxf(lm, __shfl_xor(lm, o, 64));
  if ((t & 63) == 0) red[t >> 6] = lm;
  __syncthreads();
  float m = fmaxf(fmaxf(red[0], red[1]), fmaxf(red[2], red[3]));
  float ls = 0.f;
  for (int k = t; k < KL; k += 256) {
    float p = __expf(buf[k] - m);
    buf[k] = p;
    ls += p;
  }
#pragma unroll
  for (int o = 32; o > 0; o >>= 1) ls += __shfl_xor(ls, o, 64);
  __syncthreads();   // everyone done reading red (max) before reuse
  if ((t & 63) == 0) red[t >> 6] = ls;
  __syncthreads();
  float inv = 1.f / (red[0] + red[1] + red[2] + red[3]);
  for (int k = t; k < KL; k += 256) sr[k] = buf[k] * inv;
}

// Attention mask from previous mask logits: bilinear resize 112x112 -> HkxHk,
// m = (r < 0), row fully-masked => unmask row. grid (Q, B), block 256.
__global__ __launch_bounds__(256) void amask_k(const float* __restrict__ pm,
                                               unsigned char* __restrict__ am,
                                               int Hk) {
  int b = blockIdx.y, qq = blockIdx.x, t = threadIdx.x;
  int KL = Hk * Hk;
  const float* src = pm + ((size_t)(b * QQ + qq)) * PP;
  __shared__ unsigned char mb[KMAX];
  __shared__ int wall[4];
  float sc = (float)HMM / (float)Hk;
  int localAll = 1;
  for (int k = t; k < KL; k += 256) {
    int y = k / Hk, x = k - y * Hk;
    float sy = (y + 0.5f) * sc - 0.5f;
    float sx = (x + 0.5f) * sc - 0.5f;
    int y0 = (int)floorf(sy); float fy = sy - (float)y0;
    int x0 = (int)floorf(sx); float fx = sx - (float)x0;
    int y0c = min(max(y0, 0), HMM - 1), y1c = min(max(y0 + 1, 0), HMM - 1);
    int x0c = min(max(x0, 0), HMM - 1), x1c = min(max(x0 + 1, 0), HMM - 1);
    float v00 = src[y0c * HMM + x0c], v01 = src[y0c * HMM + x1c];
    float v10 = src[y1c * HMM + x0c], v11 = src[y1c * HMM + x1c];
    float r = (1.f - fy) * ((1.f - fx) * v00 + fx * v01) +
              fy * ((1.f - fx) * v10 + fx * v11);
    unsigned char mm = (r < 0.f) ? 1 : 0;
    mb[k] = mm;
    localAll &= (int)mm;
  }
  int wa = __all(localAll);
  if ((t & 63) == 0) wall[t >> 6] = wa;
  __syncthreads();
  unsigned char notfull = (wall[0] & wall[1] & wall[2] & wall[3]) ? 0 : 1;
  unsigned char* dst = am + ((size_t)b * QQ + qq) * KL;
  for (int k = t; k < KL; k += 256) dst[k] = (unsigned char)(mb[k] & notfull);
}

// ---------------------------------------------------------------------------
// Generic tiled fp32 GEMM: C[m,n] = epi( alpha * sum_k A(m,k)*B(n,k) )
//   A(m,k) = A[k*sA + m] if AT else A[m*sA + k]
//   B(n,k) = B[k*sB + n] if BT else B[n*sB + k]
// Two-level batch via grid.z: b1 = z/nz2, b2 = z%nz2 with per-operand strides.
// Epilogue: *alpha, +bias[n], +res[m*ldc+n], mask -> -FLT_MAX, relu.
// ---------------------------------------------------------------------------
template <int BM, int BN, bool AT, bool BT>
__global__ __launch_bounds__(256) void gemm_kern(
    const float* __restrict__ A, const float* __restrict__ B,
    const float* __restrict__ bias, const float* __restrict__ res,
    const unsigned char* __restrict__ msk, float* __restrict__ C,
    int M, int N, int K, long sA, long sB, long ldc,
    int nz2, long bA1, long bA2, long bB1, long bB2, long bC1, long bC2,
    long mskB1, float alpha, int relu) {
  constexpr int BK = 16;
  constexpr int RM = BM / 16, RN = BN / 16;
  int b1 = blockIdx.z / nz2, b2 = blockIdx.z % nz2;
  A += (size_t)b1 * bA1 + (size_t)b2 * bA2;
  B += (size_t)b1 * bB1 + (size_t)b2 * bB2;
  C += (size_t)b1 * bC1 + (size_t)b2 * bC2;
  if (res) res += (size_t)b1 * bC1 + (size_t)b2 * bC2;
  int m0 = blockIdx.y * BM, n0 = blockIdx.x * BN;
  int t = threadIdx.x;
  __shared__ __align__(16) float As[BK][BM + 4];
  __shared__ __align__(16) float Bs[BK][BN + 4];
  float acc[RM][RN];
#pragma unroll
  for (int i = 0; i < RM; i++)
#pragma unroll
    for (int j = 0; j < RN; j++) acc[i][j] = 0.f;
  int ty = t / 16, tx = t % 16;
  for (int k0 = 0; k0 < K; k0 += BK) {
#pragma unroll
    for (int idx = t; idx < BM * BK; idx += 256) {
      int mm, kk;
      if constexpr (AT) { mm = idx % BM; kk = idx / BM; }
      else              { kk = idx % BK; mm = idx / BK; }
      int mq = m0 + mm, kq = k0 + kk;
      float v = 0.f;
      if (mq < M && kq < K)
        v = AT ? A[(size_t)kq * sA + mq] : A[(size_t)mq * sA + kq];
      As[kk][mm] = v;
    }
#pragma unroll
    for (int idx = t; idx < BN * BK; idx += 256) {
      int nn, kk;
      if constexpr (BT) { nn = idx % BN; kk = idx / BN; }
      else              { kk = idx % BK; nn = idx / BK; }
      int nq = n0 + nn, kq = k0 + kk;
      float v = 0.f;
      if (nq < N && kq < K)
        v = BT ? B[(size_t)kq * sB + nq] : B[(size_t)nq * sB + kq];
      Bs[kk][nn] = v;
    }
    __syncthreads();
#pragma unroll
    for (int kk = 0; kk < BK; kk++) {
      float a[RM], bb[RN];
#pragma unroll
      for (int i = 0; i < RM; i++) a[i] = As[kk][ty * RM + i];
#pragma unroll
      for (int j = 0; j < RN; j++) bb[j] = Bs[kk][tx * RN + j];
#pragma unroll
      for (int i = 0; i < RM; i++)
#pragma unroll
        for (int j = 0; j < RN; j++) acc[i][j] = fmaf(a[i], bb[j], acc[i][j]);
    }
    __syncthreads();
  }
#pragma unroll
  for (int i = 0; i < RM; i++) {
    int m = m0 + ty * RM + i;
    if (m >= M) continue;
#pragma unroll
    for (int j = 0; j < RN; j++) {
      int n = n0 + tx * RN + j;
      if (n >= N) continue;
      float v = acc[i][j] * alpha;
      if (bias) v += bias[n];
      if (res) v += res[(size_t)m * ldc + n];
      if (msk && msk[(size_t)b1 * mskB1 + (size_t)m * N + n])
        v = -3.4028234663852886e38f;
      if (relu) v = fmaxf(v, 0.f);
      C[(size_t)m * ldc + n] = v;
    }
  }
}

template <int BM, int BN, bool AT, bool BT>
static inline void rungemm(hipStream_t st, const float* A, const float* B,
                           const float* bias, const float* res,
                           const unsigned char* msk, float* C, int M, int N,
                           int K, long sA, long sB, long ldc, int nb1, int nz2,
                           long bA1, long bA2, long bB1, long bB2, long bC1,
                           long bC2, long mskB1, float alpha, int relu) {
  dim3 g((N + BN - 1) / BN, (M + BM - 1) / BM, nb1 * nz2);
  gemm_kern<BM, BN, AT, BT><<<g, dim3(256), 0, st>>>(
      A, B, bias, res, msk, C, M, N, K, sA, sB, ldc, nz2, bA1, bA2, bB1, bB2,
      bC1, bC2, mskB1, alpha, relu);
}

extern "C" void kernel_launch(void* const* d_in, const int* in_sizes, int n_in,
                              void* d_out, int out_size, void* d_ws,
                              size_t ws_size, hipStream_t stream) {
  const float* mfeat = (const float*)d_in[0];   // [B,256,12544]
  const float* mems[3] = {(const float*)d_in[1], (const float*)d_in[2],
                          (const float*)d_in[3]};
  const int Hks[3] = {14, 28, 56};
  const float* qf = (const float*)d_in[4];
  const float* qe = (const float*)d_in[5];
  const float* ca_in_w = (const float*)d_in[6];
  const float* ca_in_b = (const float*)d_in[7];
  const float* ca_out_w = (const float*)d_in[8];
  const float* ca_out_b = (const float*)d_in[9];
  const float* ca_ln_g = (const float*)d_in[10];
  const float* ca_ln_b = (const float*)d_in[11];
  const float* sa_in_w = (const float*)d_in[12];
  const float* sa_in_b = (const float*)d_in[13];
  const float* sa_out_w = (const float*)d_in[14];
  const float* sa_out_b = (const float*)d_in[15];
  const float* sa_ln_g = (const float*)d_in[16];
  const float* sa_ln_b = (const float*)d_in[17];
  const float* ffn_w1 = (const float*)d_in[18];
  const float* ffn_b1 = (const float*)d_in[19];
  const float* ffn_w2 = (const float*)d_in[20];
  const float* ffn_b2 = (const float*)d_in[21];
  const float* ffn_ln_g = (const float*)d_in[22];
  const float* ffn_ln_b = (const float*)d_in[23];
  const float* cls_w = (const float*)d_in[24];
  const float* cls_b = (const float*)d_in[25];
  const float* me_w1 = (const float*)d_in[26];
  const float* me_b1 = (const float*)d_in[27];
  const float* me_w2 = (const float*)d_in[28];
  const float* me_b2 = (const float*)d_in[29];
  const float* me_w3 = (const float*)d_in[30];
  const float* me_b3 = (const float*)d_in[31];
  const float* dn_g = (const float*)d_in[32];
  const float* dn_b = (const float*)d_in[33];

  // Output layout: [pl_last (8,100,151)][pm_last (8,100,112,112)]
  //                [aux_l (8,8,100,151)][aux_m (8,8,100,112,112)]
  float* out0 = (float*)d_out;
  float* out1 = out0 + (size_t)BB * QQ * NCC;            // 120800
  float* out2 = out1 + (size_t)BB * QQ * PP;             // +10035200
  float* out3 = out2 + (size_t)8 * BB * QQ * NCC;        // +966400

  // Workspace carve-up (floats).
  float* w = (float*)d_ws;
  auto alloc = [&](size_t n) { float* p = w; w += n; return p; };
  float* q = alloc((size_t)BB * QQ * DD);       // 204800
  float* qh = alloc((size_t)BB * QQ * DD);
  float* tmp = alloc((size_t)BB * QQ * DD);
  float* nq = alloc((size_t)BB * QQ * DD);
  float* obuf = alloc((size_t)BB * QQ * DD);
  float* mea = alloc((size_t)BB * QQ * DD);
  float* meb = alloc((size_t)BB * QQ * DD);
  float* mec = alloc((size_t)BB * QQ * DD);
  float* saqkv = alloc((size_t)BB * QQ * 3 * DD);        // 614400
  float* ffnbuf = alloc((size_t)BB * QQ * FFD);          // 1638400
  float* kv = alloc((size_t)BB * KMAX * 2 * DD);         // 12845056
  float* sbuf = alloc((size_t)BB * NHH * QQ * KMAX);     // 20070400
  unsigned char* amask = (unsigned char*)w;              // 2508800 bytes

  const float scale = 0.17677669529663687f;  // 1/sqrt(32)

  initq_k<<<dim3(800), dim3(256), 0, stream>>>(qf, qe, q);

  const float* prevPm = nullptr;
  for (int i = 0; i < LL; i++) {
    int mi = i % 3;
    int Hk = Hks[mi];
    int KL = Hk * Hk;
    const float* mem = mems[mi];
    const float* caw = ca_in_w + (size_t)i * 3 * DD * DD;
    const float* cab = ca_in_b + (size_t)i * 3 * DD;
    const float* caow = ca_out_w + (size_t)i * DD * DD;
    const float* caob = ca_out_b + (size_t)i * DD;
    const float* calg = ca_ln_g + (size_t)i * DD;
    const float* calb = ca_ln_b + (size_t)i * DD;
    const float* saw = sa_in_w + (size_t)i * 3 * DD * DD;
    const float* sab = sa_in_b + (size_t)i * 3 * DD;
    const float* saow = sa_out_w + (size_t)i * DD * DD;
    const float* saob = sa_out_b + (size_t)i * DD;
    const float* salg = sa_ln_g + (size_t)i * DD;
    const float* salb = sa_ln_b + (size_t)i * DD;
    const float* fw1 = ffn_w1 + (size_t)i * FFD * DD;
    const float* fb1 = ffn_b1 + (size_t)i * FFD;
    const float* fw2 = ffn_w2 + (size_t)i * DD * FFD;
    const float* fb2 = ffn_b2 + (size_t)i * DD;
    const float* flg = ffn_ln_g + (size_t)i * DD;
    const float* flb = ffn_ln_b + (size_t)i * DD;

    // ---- attention mask from previous layer's mask logits ----
    if (i > 0)
      amask_k<<<dim3(QQ, BB), dim3(256), 0, stream>>>(prevPm, amask, Hk);

    // ---- cross attention ----
    // q projection: [800,256] x wq[256,256]^T + bq -> qh [800,256]
    rungemm<32, 32, false, false>(stream, q, caw, cab, nullptr, nullptr, qh,
                                  800, DD, DD, DD, DD, DD, 1, 1, 0, 0, 0, 0, 0,
                                  0, 0, 1.f, 0);
    // kv projection (A = mem[b] stored [256, KL], i.e. memf^T): per-b
    // C[kk, n] for n in [0,512): n<256 -> k, else v. kv layout [B,KL,512].
    rungemm<64, 64, true, false>(stream, mem, caw + DD * DD, cab + DD, nullptr,
                                 nullptr, kv, KL, 2 * DD, DD, KL, DD, 2 * DD,
                                 BB, 1, (long)DD * KL, 0, 0, 0, (long)KL * 2 * DD,
                                 0, 0, 1.f, 0);
    // scores: per (b,h): qh[100,32] x k[KL,32]^T * scale, mask -> sbuf
    rungemm<64, 64, false, false>(
        stream, qh, kv, nullptr, nullptr, (i > 0 ? amask : nullptr), sbuf, QQ,
        KL, HDD, DD, 2 * DD, KL, BB, NHH, (long)QQ * DD, HDD,
        (long)KL * 2 * DD, HDD, (long)NHH * QQ * KL, (long)QQ * KL,
        (long)QQ * KL, scale, 0);
    softmax_k<<<dim3(BB * NHH * QQ), dim3(256), 0, stream>>>(sbuf, KL);
    // attn @ V: per (b,h): p[100,KL] x v[KL,32] -> obuf[b,q,h*32+d]
    rungemm<32, 32, false, true>(stream, sbuf, kv + DD, nullptr, nullptr,
                                 nullptr, obuf, QQ, HDD, KL, KL, 2 * DD, DD,
                                 BB, NHH, (long)NHH * QQ * KL, (long)QQ * KL,
                                 (long)KL * 2 * DD, HDD, (long)QQ * DD, HDD, 0,
                                 1.f, 0);
    // out proj + residual(q) -> tmp, then LN -> q
    rungemm<32, 32, false, false>(stream, obuf, caow, caob, q, nullptr, tmp,
                                  800, DD, DD, DD, DD, DD, 1, 1, 0, 0, 0, 0, 0,
                                  0, 0, 1.f, 0);
    ln_k<<<dim3(800), dim3(64), 0, stream>>>(tmp, calg, calb, q);

    // ---- self attention ----
    rungemm<32, 32, false, false>(stream, q, saw, sab, nullptr, nullptr, saqkv,
                                  800, 3 * DD, DD, DD, DD, 3 * DD, 1, 1, 0, 0,
                                  0, 0, 0, 0, 0, 1.f, 0);
    rungemm<32, 32, false, false>(
        stream, saqkv, saqkv + DD, nullptr, nullptr, nullptr, sbuf, QQ, QQ,
        HDD, 3 * DD, 3 * DD, QQ, BB, NHH, (long)QQ * 3 * DD, HDD,
        (long)QQ * 3 * DD, HDD, (long)NHH * QQ * QQ, (long)QQ * QQ, 0, scale,
        0);
    softmax_k<<<dim3(BB * NHH * QQ), dim3(256), 0, stream>>>(sbuf, QQ);
    rungemm<32, 32, false, true>(stream, sbuf, saqkv + 2 * DD, nullptr,
                                 nullptr, nullptr, obuf, QQ, HDD, QQ, QQ,
                                 3 * DD, DD, BB, NHH, (long)NHH * QQ * QQ,
                                 (long)QQ * QQ, (long)QQ * 3 * DD, HDD,
                                 (long)QQ * DD, HDD, 0, 1.f, 0);
    rungemm<32, 32, false, false>(stream, obuf, saow, saob, q, nullptr, tmp,
                                  800, DD, DD, DD, DD, DD, 1, 1, 0, 0, 0, 0, 0,
                                  0, 0, 1.f, 0);
    ln_k<<<dim3(800), dim3(64), 0, stream>>>(tmp, salg, salb, q);

    // ---- FFN ----
    rungemm<64, 64, false, false>(stream, q, fw1, fb1, nullptr, nullptr,
                                  ffnbuf, 800, FFD, DD, DD, DD, FFD, 1, 1, 0,
                                  0, 0, 0, 0, 0, 0, 1.f, 1);
    rungemm<32, 32, false, false>(stream, ffnbuf, fw2, fb2, q, nullptr, tmp,
                                  800, DD, FFD, FFD, FFD, DD, 1, 1, 0, 0, 0, 0,
                                  0, 0, 0, 1.f, 0);
    ln_k<<<dim3(800), dim3(64), 0, stream>>>(tmp, flg, flb, q);

    // ---- decoder norm + heads ----
    ln_k<<<dim3(800), dim3(64), 0, stream>>>(q, dn_g, dn_b, nq);
    rungemm<32, 32, false, false>(stream, nq, me_w1, me_b1, nullptr, nullptr,
                                  mea, 800, DD, DD, DD, DD, DD, 1, 1, 0, 0, 0,
                                  0, 0, 0, 0, 1.f, 1);
    rungemm<32, 32, false, false>(stream, mea, me_w2, me_b2, nullptr, nullptr,
                                  meb, 800, DD, DD, DD, DD, DD, 1, 1, 0, 0, 0,
                                  0, 0, 0, 0, 1.f, 1);
    rungemm<32, 32, false, false>(stream, meb, me_w3, me_b3, nullptr, nullptr,
                                  mec, 800, DD, DD, DD, DD, DD, 1, 1, 0, 0, 0,
                                  0, 0, 0, 0, 1.f, 0);
    float* pl = (i < 8) ? (out2 + (size_t)i * BB * QQ * NCC) : out0;
    rungemm<32, 32, false, false>(stream, nq, cls_w, cls_b, nullptr, nullptr,
                                  pl, 800, NCC, DD, DD, DD, NCC, 1, 1, 0, 0, 0,
                                  0, 0, 0, 0, 1.f, 0);
    // mask logits: per-b: mec[100,256] x mfeat[b][256,12544] -> pm
    float* pmOut = (i < 8) ? (out3 + (size_t)i * BB * QQ * PP) : out1;
    rungemm<64, 64, false, true>(stream, mec, mfeat, nullptr, nullptr, nullptr,
                                 pmOut, QQ, PP, DD, DD, PP, PP, BB, 1,
                                 (long)QQ * DD, 0, (long)DD * PP, 0,
                                 (long)QQ * PP, 0, 0, 1.f, 0);
    prevPm = pmOut;
  }
}

// Round 2
// 4511.826 us; speedup vs baseline: 1.7601x; 1.7601x over previous
//
#include <hip/hip_runtime.h>
#include <hip/hip_bf16.h>

// ---------------------------------------------------------------------------
// Mask2Former transformer decoder, fp32. Round 2: vectorized GEMM staging,
// split-K for K-heavy GEMMs, bigger tiles for kv-proj / mask-einsum.
// ---------------------------------------------------------------------------

#define LL 9
#define DD 256
#define QQ 100
#define NHH 8
#define HDD 32
#define FFD 2048
#define NCC 151
#define BB 8
#define HMM 112
#define PP (HMM*HMM)      // 12544
#define KMAX 3136

__global__ void initq_k(const float* __restrict__ qf, const float* __restrict__ qe,
                        float* __restrict__ q) {
  int idx = blockIdx.x * 256 + threadIdx.x;       // 800*256 = 204800
  int qd = idx % (QQ * DD);
  q[idx] = qf[qd] + qe[qd];
}

// LayerNorm over D=256. grid = rows (800), block = 64 (one wave).
__global__ __launch_bounds__(64) void ln_k(const float* __restrict__ x,
                                           const float* __restrict__ g,
                                           const float* __restrict__ b,
                                           float* __restrict__ y) {
  int r = blockIdx.x, t = threadIdx.x;
  const float* xr = x + (size_t)r * DD;
  float* yr = y + (size_t)r * DD;
  float v[4];
  float s = 0.f, sq = 0.f;
#pragma unroll
  for (int i = 0; i < 4; i++) {
    v[i] = xr[t + 64 * i];
    s += v[i];
    sq += v[i] * v[i];
  }
#pragma unroll
  for (int o = 32; o > 0; o >>= 1) {
    s += __shfl_xor(s, o, 64);
    sq += __shfl_xor(sq, o, 64);
  }
  float mean = s * (1.f / DD);
  float var = sq * (1.f / DD) - mean * mean;
  float rs = rsqrtf(var + 1e-5f);
#pragma unroll
  for (int i = 0; i < 4; i++) {
    int c = t + 64 * i;
    yr[c] = g[c] * (v[i] - mean) * rs + b[c];
  }
}

// Row softmax in-place. grid = rows, block 256. KL <= 3136.
__global__ __launch_bounds__(256) void softmax_k(float* __restrict__ s, int KL) {
  int row = blockIdx.x, t = threadIdx.x;
  float* sr = s + (size_t)row * KL;
  __shared__ float buf[KMAX];
  __shared__ float red[4];
  float lm = -3.402823466e38f;
  for (int k = t; k < KL; k += 256) {
    float v = sr[k];
    buf[k] = v;
    lm = fmaxf(lm, v);
  }
#pragma unroll
  for (int o = 32; o > 0; o >>= 1) lm = fmaxf(lm, __shfl_xor(lm, o, 64));
  if ((t & 63) == 0) red[t >> 6] = lm;
  __syncthreads();
  float m = fmaxf(fmaxf(red[0], red[1]), fmaxf(red[2], red[3]));
  float ls = 0.f;
  for (int k = t; k < KL; k += 256) {
    float p = __expf(buf[k] - m);
    buf[k] = p;
    ls += p;
  }
#pragma unroll
  for (int o = 32; o > 0; o >>= 1) ls += __shfl_xor(ls, o, 64);
  __syncthreads();
  if ((t & 63) == 0) red[t >> 6] = ls;
  __syncthreads();
  float inv = 1.f / (red[0] + red[1] + red[2] + red[3]);
  for (int k = t; k < KL; k += 256) sr[k] = buf[k] * inv;
}

// Attention mask: bilinear resize 112x112 -> HkxHk, m=(r<0), full row unmask.
__global__ __launch_bounds__(256) void amask_k(const float* __restrict__ pm,
                                               unsigned char* __restrict__ am,
                                               int Hk) {
  int b = blockIdx.y, qq = blockIdx.x, t = threadIdx.x;
  int KL = Hk * Hk;
  const float* src = pm + ((size_t)(b * QQ + qq)) * PP;
  __shared__ unsigned char mb[KMAX];
  __shared__ int wall[4];
  float sc = (float)HMM / (float)Hk;
  int localAll = 1;
  for (int k = t; k < KL; k += 256) {
    int y = k / Hk, x = k - y * Hk;
    float sy = (y + 0.5f) * sc - 0.5f;
    float sx = (x + 0.5f) * sc - 0.5f;
    int y0 = (int)floorf(sy); float fy = sy - (float)y0;
    int x0 = (int)floorf(sx); float fx = sx - (float)x0;
    int y0c = min(max(y0, 0), HMM - 1), y1c = min(max(y0 + 1, 0), HMM - 1);
    int x0c = min(max(x0, 0), HMM - 1), x1c = min(max(x0 + 1, 0), HMM - 1);
    float v00 = src[y0c * HMM + x0c], v01 = src[y0c * HMM + x1c];
    float v10 = src[y1c * HMM + x0c], v11 = src[y1c * HMM + x1c];
    float r = (1.f - fy) * ((1.f - fx) * v00 + fx * v01) +
              fy * ((1.f - fx) * v10 + fx * v11);
    unsigned char mm = (r < 0.f) ? 1 : 0;
    mb[k] = mm;
    localAll &= (int)mm;
  }
  int wa = __all(localAll);
  if ((t & 63) == 0) wall[t >> 6] = wa;
  __syncthreads();
  unsigned char notfull = (wall[0] & wall[1] & wall[2] & wall[3]) ? 0 : 1;
  unsigned char* dst = am + ((size_t)b * QQ + qq) * KL;
  for (int k = t; k < KL; k += 256) dst[k] = (unsigned char)(mb[k] & notfull);
}

// Reduce split-K partials for ffn2: out = sum_sk part + bias[n] + res.
__global__ __launch_bounds__(256) void reduceff_k(const float* __restrict__ part,
                                                  float* __restrict__ out,
                                                  const float* __restrict__ bias,
                                                  const float* __restrict__ res,
                                                  int SK) {
  int idx = blockIdx.x * 256 + threadIdx.x;     // 204800
  float s = 0.f;
  for (int k = 0; k < SK; k++) s += part[(size_t)k * 204800 + idx];
  out[idx] = s + bias[idx & 255] + res[idx];
}

// Reduce split-K partials for attn@V: part[sk][bh][m][n] -> obuf[b][m][h*32+n].
__global__ __launch_bounds__(256) void reducepv_k(const float* __restrict__ part,
                                                  float* __restrict__ out, int SK) {
  int idx = blockIdx.x * 256 + threadIdx.x;     // 204800
  float s = 0.f;
  for (int k = 0; k < SK; k++) s += part[(size_t)k * 204800 + idx];
  int bh = idx / 3200, r = idx % 3200, m = r / 32, n = r % 32;
  out[(size_t)(bh >> 3) * 25600 + m * 256 + (bh & 7) * 32 + n] = s;
}

// ---------------------------------------------------------------------------
// Generic tiled fp32 GEMM: C = epi( alpha * A(m,k) * B(n,k) )
//   A(m,k) = A[k*sA + m] if AT else A[m*sA + k]
//   B(n,k) = B[k*sB + n] if BT else B[n*sB + k]
// Three-level batch via grid.z: z -> (b1, b2, b3) with per-operand strides.
// Requirements exploited for float4 loads: K%4==0; (AT -> M%4==0);
// (BT -> N%4==0); all row strides %4==0; all base offsets %4==0.
// ---------------------------------------------------------------------------
template <int BM, int BN, int BK, bool AT, bool BT>
__global__ __launch_bounds__(256) void gemm_kern(
    const float* __restrict__ A, const float* __restrict__ B,
    const float* __restrict__ bias, const float* __restrict__ res,
    const unsigned char* __restrict__ msk, float* __restrict__ C,
    int M, int N, int K, long sA, long sB, long ldc,
    int nz2, int nz3,
    long bA1, long bA2, long bA3, long bB1, long bB2, long bB3,
    long bC1, long bC2, long bC3, long mskB1, float alpha, int relu) {
  constexpr int RM = BM / 16, RN = BN / 16;
  int z = blockIdx.z;
  int b3 = z % nz3; int zz = z / nz3;
  int b2 = zz % nz2; int b1 = zz / nz2;
  A += (size_t)b1 * bA1 + (size_t)b2 * bA2 + (size_t)b3 * bA3;
  B += (size_t)b1 * bB1 + (size_t)b2 * bB2 + (size_t)b3 * bB3;
  C += (size_t)b1 * bC1 + (size_t)b2 * bC2 + (size_t)b3 * bC3;
  if (res) res += (size_t)b1 * bC1 + (size_t)b2 * bC2 + (size_t)b3 * bC3;
  const unsigned char* mrow = msk ? msk + (size_t)b1 * mskB1 : nullptr;
  int m0 = blockIdx.y * BM, n0 = blockIdx.x * BN;
  int t = threadIdx.x;
  __shared__ __align__(16) float As[BK][BM + 4];
  __shared__ __align__(16) float Bs[BK][BN + 4];
  float acc[RM][RN];
#pragma unroll
  for (int i = 0; i < RM; i++)
#pragma unroll
    for (int j = 0; j < RN; j++) acc[i][j] = 0.f;
  int ty = t / 16, tx = t % 16;
  for (int k0 = 0; k0 < K; k0 += BK) {
    // ---- stage A ----
    if constexpr (!AT) {
      constexpr int NV = BM * BK / 4;
#pragma unroll
      for (int idx = t; idx < NV; idx += 256) {
        int k4 = idx % (BK / 4), mm = idx / (BK / 4);
        int mq = m0 + mm, kq = k0 + k4 * 4;
        float4 v = make_float4(0.f, 0.f, 0.f, 0.f);
        if (mq < M && kq < K) v = *(const float4*)(A + (size_t)mq * sA + kq);
        As[k4 * 4 + 0][mm] = v.x; As[k4 * 4 + 1][mm] = v.y;
        As[k4 * 4 + 2][mm] = v.z; As[k4 * 4 + 3][mm] = v.w;
      }
    } else {
      constexpr int NV = BM * BK / 4;
#pragma unroll
      for (int idx = t; idx < NV; idx += 256) {
        int m4 = idx % (BM / 4), kk = idx / (BM / 4);
        int mq = m0 + m4 * 4, kq = k0 + kk;
        float4 v = make_float4(0.f, 0.f, 0.f, 0.f);
        if (mq < M && kq < K) v = *(const float4*)(A + (size_t)kq * sA + mq);
        *(float4*)&As[kk][m4 * 4] = v;
      }
    }
    // ---- stage B ----
    if constexpr (!BT) {
      constexpr int NV = BN * BK / 4;
#pragma unroll
      for (int idx = t; idx < NV; idx += 256) {
        int k4 = idx % (BK / 4), nn = idx / (BK / 4);
        int nq = n0 + nn, kq = k0 + k4 * 4;
        float4 v = make_float4(0.f, 0.f, 0.f, 0.f);
        if (nq < N && kq < K) v = *(const float4*)(B + (size_t)nq * sB + kq);
        Bs[k4 * 4 + 0][nn] = v.x; Bs[k4 * 4 + 1][nn] = v.y;
        Bs[k4 * 4 + 2][nn] = v.z; Bs[k4 * 4 + 3][nn] = v.w;
      }
    } else {
      constexpr int NV = BN * BK / 4;
#pragma unroll
      for (int idx = t; idx < NV; idx += 256) {
        int n4 = idx % (BN / 4), kk = idx / (BN / 4);
        int nq = n0 + n4 * 4, kq = k0 + kk;
        float4 v = make_float4(0.f, 0.f, 0.f, 0.f);
        if (nq < N && kq < K) v = *(const float4*)(B + (size_t)kq * sB + nq);
        *(float4*)&Bs[kk][n4 * 4] = v;
      }
    }
    __syncthreads();
#pragma unroll
    for (int kk = 0; kk < BK; kk++) {
      float a[RM], bb[RN];
#pragma unroll
      for (int i = 0; i < RM; i++) a[i] = As[kk][ty * RM + i];
#pragma unroll
      for (int j = 0; j < RN; j++) bb[j] = Bs[kk][tx * RN + j];
#pragma unroll
      for (int i = 0; i < RM; i++)
#pragma unroll
        for (int j = 0; j < RN; j++) acc[i][j] = fmaf(a[i], bb[j], acc[i][j]);
    }
    __syncthreads();
  }
  // ---- epilogue ----
  bool vecC = ((ldc & 3) == 0) && ((N & 3) == 0) && (msk == nullptr) &&
              ((RN & 3) == 0);
#pragma unroll
  for (int i = 0; i < RM; i++) {
    int m = m0 + ty * RM + i;
    if (m >= M) continue;
    size_t rowoff = (size_t)m * ldc;
    if (vecC) {
#pragma unroll
      for (int j4 = 0; j4 < RN; j4 += 4) {
        int n = n0 + tx * RN + j4;
        if (n >= N) continue;
        float4 v;
        v.x = acc[i][j4 + 0] * alpha; v.y = acc[i][j4 + 1] * alpha;
        v.z = acc[i][j4 + 2] * alpha; v.w = acc[i][j4 + 3] * alpha;
        if (bias) { v.x += bias[n]; v.y += bias[n+1]; v.z += bias[n+2]; v.w += bias[n+3]; }
        if (res) {
          float4 r = *(const float4*)(res + rowoff + n);
          v.x += r.x; v.y += r.y; v.z += r.z; v.w += r.w;
        }
        if (relu) {
          v.x = fmaxf(v.x, 0.f); v.y = fmaxf(v.y, 0.f);
          v.z = fmaxf(v.z, 0.f); v.w = fmaxf(v.w, 0.f);
        }
        *(float4*)(C + rowoff + n) = v;
      }
    } else {
#pragma unroll
      for (int j = 0; j < RN; j++) {
        int n = n0 + tx * RN + j;
        if (n >= N) continue;
        float v = acc[i][j] * alpha;
        if (bias) v += bias[n];
        if (res) v += res[rowoff + n];
        if (mrow && mrow[(size_t)m * N + n]) v = -3.4028234663852886e38f;
        if (relu) v = fmaxf(v, 0.f);
        C[rowoff + n] = v;
      }
    }
  }
}

template <int BM, int BN, int BK, bool AT, bool BT>
static inline void rungemm(hipStream_t st, const float* A, const float* B,
                           const float* bias, const float* res,
                           const unsigned char* msk, float* C, int M, int N,
                           int K, long sA, long sB, long ldc,
                           int nb1, int nz2, int nz3,
                           long bA1, long bA2, long bA3,
                           long bB1, long bB2, long bB3,
                           long bC1, long bC2, long bC3,
                           long mskB1, float alpha, int relu) {
  dim3 g((N + BN - 1) / BN, (M + BM - 1) / BM, nb1 * nz2 * nz3);
  gemm_kern<BM, BN, BK, AT, BT><<<g, dim3(256), 0, st>>>(
      A, B, bias, res, msk, C, M, N, K, sA, sB, ldc, nz2, nz3,
      bA1, bA2, bA3, bB1, bB2, bB3, bC1, bC2, bC3, mskB1, alpha, relu);
}

extern "C" void kernel_launch(void* const* d_in, const int* in_sizes, int n_in,
                              void* d_out, int out_size, void* d_ws,
                              size_t ws_size, hipStream_t stream) {
  const float* mfeat = (const float*)d_in[0];   // [B,256,12544]
  const float* mems[3] = {(const float*)d_in[1], (const float*)d_in[2],
                          (const float*)d_in[3]};
  const int Hks[3] = {14, 28, 56};
  const float* qf = (const float*)d_in[4];
  const float* qe = (const float*)d_in[5];
  const float* ca_in_w = (const float*)d_in[6];
  const float* ca_in_b = (const float*)d_in[7];
  const float* ca_out_w = (const float*)d_in[8];
  const float* ca_out_b = (const float*)d_in[9];
  const float* ca_ln_g = (const float*)d_in[10];
  const float* ca_ln_b = (const float*)d_in[11];
  const float* sa_in_w = (const float*)d_in[12];
  const float* sa_in_b = (const float*)d_in[13];
  const float* sa_out_w = (const float*)d_in[14];
  const float* sa_out_b = (const float*)d_in[15];
  const float* sa_ln_g = (const float*)d_in[16];
  const float* sa_ln_b = (const float*)d_in[17];
  const float* ffn_w1 = (const float*)d_in[18];
  const float* ffn_b1 = (const float*)d_in[19];
  const float* ffn_w2 = (const float*)d_in[20];
  const float* ffn_b2 = (const float*)d_in[21];
  const float* ffn_ln_g = (const float*)d_in[22];
  const float* ffn_ln_b = (const float*)d_in[23];
  const float* cls_w = (const float*)d_in[24];
  const float* cls_b = (const float*)d_in[25];
  const float* me_w1 = (const float*)d_in[26];
  const float* me_b1 = (const float*)d_in[27];
  const float* me_w2 = (const float*)d_in[28];
  const float* me_b2 = (const float*)d_in[29];
  const float* me_w3 = (const float*)d_in[30];
  const float* me_b3 = (const float*)d_in[31];
  const float* dn_g = (const float*)d_in[32];
  const float* dn_b = (const float*)d_in[33];

  float* out0 = (float*)d_out;
  float* out1 = out0 + (size_t)BB * QQ * NCC;
  float* out2 = out1 + (size_t)BB * QQ * PP;
  float* out3 = out2 + (size_t)8 * BB * QQ * NCC;

  float* w = (float*)d_ws;
  auto alloc = [&](size_t n) { float* p = w; w += n; return p; };
  float* q = alloc((size_t)BB * QQ * DD);       // 204800
  float* qh = alloc((size_t)BB * QQ * DD);
  float* tmp = alloc((size_t)BB * QQ * DD);
  float* nq = alloc((size_t)BB * QQ * DD);
  float* obuf = alloc((size_t)BB * QQ * DD);
  float* mea = alloc((size_t)BB * QQ * DD);
  float* meb = alloc((size_t)BB * QQ * DD);
  float* mec = alloc((size_t)BB * QQ * DD);
  float* saqkv = alloc((size_t)BB * QQ * 3 * DD);
  float* ffnbuf = alloc((size_t)BB * QQ * FFD);          // 1638400 (alias: pv partials)
  float* kv = alloc((size_t)BB * KMAX * 2 * DD);
  float* sbuf = alloc((size_t)BB * NHH * QQ * KMAX);     // (alias: ffn2 partials)
  unsigned char* amask = (unsigned char*)w;
  float* pvpart = ffnbuf;   // [SK][64][100][32], SK<=8 -> 1638400 floats max
  float* ff2part = sbuf;    // [8][800][256] -> 1638400 floats

  const float scale = 0.17677669529663687f;  // 1/sqrt(32)

  initq_k<<<dim3(800), dim3(256), 0, stream>>>(qf, qe, q);

  const float* prevPm = nullptr;
  for (int i = 0; i < LL; i++) {
    int mi = i % 3;
    int Hk = Hks[mi];
    int KL = Hk * Hk;
    const float* mem = mems[mi];
    const float* caw = ca_in_w + (size_t)i * 3 * DD * DD;
    const float* cab = ca_in_b + (size_t)i * 3 * DD;
    const float* caow = ca_out_w + (size_t)i * DD * DD;
    const float* caob = ca_out_b + (size_t)i * DD;
    const float* calg = ca_ln_g + (size_t)i * DD;
    const float* calb = ca_ln_b + (size_t)i * DD;
    const float* saw = sa_in_w + (size_t)i * 3 * DD * DD;
    const float* sab = sa_in_b + (size_t)i * 3 * DD;
    const float* saow = sa_out_w + (size_t)i * DD * DD;
    const float* saob = sa_out_b + (size_t)i * DD;
    const float* salg = sa_ln_g + (size_t)i * DD;
    const float* salb = sa_ln_b + (size_t)i * DD;
    const float* fw1 = ffn_w1 + (size_t)i * FFD * DD;
    const float* fb1 = ffn_b1 + (size_t)i * FFD;
    const float* fw2 = ffn_w2 + (size_t)i * DD * FFD;
    const float* fb2 = ffn_b2 + (size_t)i * DD;
    const float* flg = ffn_ln_g + (size_t)i * DD;
    const float* flb = ffn_ln_b + (size_t)i * DD;

    if (i > 0)
      amask_k<<<dim3(QQ, BB), dim3(256), 0, stream>>>(prevPm, amask, Hk);

    // ---- cross attention ----
    // q projection
    rungemm<32, 32, 16, false, false>(stream, q, caw, cab, nullptr, nullptr,
                                      qh, 800, DD, DD, DD, DD, DD,
                                      1, 1, 1, 0,0,0, 0,0,0, 0,0,0, 0, 1.f, 0);
    // kv projection: A = mem[b] (AT, [256,KL]); C = kv [B,KL,512]
    if (KL == 196)
      rungemm<64, 64, 16, true, false>(stream, mem, caw + DD * DD, cab + DD,
          nullptr, nullptr, kv, KL, 2 * DD, DD, KL, DD, 2 * DD,
          BB, 1, 1, (long)DD * KL, 0, 0, 0, 0, 0, (long)KL * 2 * DD, 0, 0,
          0, 1.f, 0);
    else
      rungemm<64, 128, 16, true, false>(stream, mem, caw + DD * DD, cab + DD,
          nullptr, nullptr, kv, KL, 2 * DD, DD, KL, DD, 2 * DD,
          BB, 1, 1, (long)DD * KL, 0, 0, 0, 0, 0, (long)KL * 2 * DD, 0, 0,
          0, 1.f, 0);
    // scores
    rungemm<64, 64, 16, false, false>(stream, qh, kv, nullptr, nullptr,
        (i > 0 ? amask : nullptr), sbuf, QQ, KL, HDD, DD, 2 * DD, KL,
        BB, NHH, 1, (long)QQ * DD, HDD, 0, (long)KL * 2 * DD, HDD, 0,
        (long)NHH * QQ * KL, (long)QQ * KL, 0, (long)QQ * KL, scale, 0);
    softmax_k<<<dim3(BB * NHH * QQ), dim3(256), 0, stream>>>(sbuf, KL);
    // attn @ V
    if (KL == 196) {
      rungemm<32, 32, 16, false, true>(stream, sbuf, kv + DD, nullptr, nullptr,
          nullptr, obuf, QQ, HDD, KL, KL, 2 * DD, DD,
          BB, NHH, 1, (long)NHH * QQ * KL, (long)QQ * KL, 0,
          (long)KL * 2 * DD, HDD, 0, (long)QQ * DD, HDD, 0, 0, 1.f, 0);
    } else {
      int SK = (KL == 784) ? 4 : 8;
      int KLc = KL / SK;
      rungemm<32, 32, 16, false, true>(stream, sbuf, kv + DD, nullptr, nullptr,
          nullptr, pvpart, QQ, HDD, KLc, KL, 2 * DD, HDD,
          BB, NHH, SK, (long)NHH * QQ * KL, (long)QQ * KL, KLc,
          (long)KL * 2 * DD, HDD, (long)KLc * 2 * DD,
          (long)NHH * QQ * HDD, (long)QQ * HDD, (long)BB * NHH * QQ * HDD,
          0, 1.f, 0);
      reducepv_k<<<dim3(800), dim3(256), 0, stream>>>(pvpart, obuf, SK);
    }
    // out proj + residual, LN
    rungemm<32, 32, 16, false, false>(stream, obuf, caow, caob, q, nullptr,
                                      tmp, 800, DD, DD, DD, DD, DD,
                                      1, 1, 1, 0,0,0, 0,0,0, 0,0,0, 0, 1.f, 0);
    ln_k<<<dim3(800), dim3(64), 0, stream>>>(tmp, calg, calb, q);

    // ---- self attention ----
    rungemm<32, 32, 16, false, false>(stream, q, saw, sab, nullptr, nullptr,
                                      saqkv, 800, 3 * DD, DD, DD, DD, 3 * DD,
                                      1, 1, 1, 0,0,0, 0,0,0, 0,0,0, 0, 1.f, 0);
    rungemm<32, 32, 16, false, false>(stream, saqkv, saqkv + DD, nullptr,
        nullptr, nullptr, sbuf, QQ, QQ, HDD, 3 * DD, 3 * DD, QQ,
        BB, NHH, 1, (long)QQ * 3 * DD, HDD, 0, (long)QQ * 3 * DD, HDD, 0,
        (long)NHH * QQ * QQ, (long)QQ * QQ, 0, 0, scale, 0);
    softmax_k<<<dim3(BB * NHH * QQ), dim3(256), 0, stream>>>(sbuf, QQ);
    rungemm<32, 32, 16, false, true>(stream, sbuf, saqkv + 2 * DD, nullptr,
        nullptr, nullptr, obuf, QQ, HDD, QQ, QQ, 3 * DD, DD,
        BB, NHH, 1, (long)NHH * QQ * QQ, (long)QQ * QQ, 0,
        (long)QQ * 3 * DD, HDD, 0, (long)QQ * DD, HDD, 0, 0, 1.f, 0);
    rungemm<32, 32, 16, false, false>(stream, obuf, saow, saob, q, nullptr,
                                      tmp, 800, DD, DD, DD, DD, DD,
                                      1, 1, 1, 0,0,0, 0,0,0, 0,0,0, 0, 1.f, 0);
    ln_k<<<dim3(800), dim3(64), 0, stream>>>(tmp, salg, salb, q);

    // ---- FFN ----
    rungemm<64, 64, 32, false, false>(stream, q, fw1, fb1, nullptr, nullptr,
                                      ffnbuf, 800, FFD, DD, DD, DD, FFD,
                                      1, 1, 1, 0,0,0, 0,0,0, 0,0,0, 0, 1.f, 1);
    // ffn2 split-K=8 into ff2part, then reduce(+bias+res)
    rungemm<64, 64, 32, false, false>(stream, ffnbuf, fw2, nullptr, nullptr,
        nullptr, ff2part, 800, DD, FFD / 8, FFD, FFD, DD,
        1, 1, 8, 0, 0, FFD / 8, 0, 0, FFD / 8, 0, 0, (long)800 * DD,
        0, 1.f, 0);
    reduceff_k<<<dim3(800), dim3(256), 0, stream>>>(ff2part, tmp, fb2, q, 8);
    ln_k<<<dim3(800), dim3(64), 0, stream>>>(tmp, flg, flb, q);

    // ---- decoder norm + heads ----
    ln_k<<<dim3(800), dim3(64), 0, stream>>>(q, dn_g, dn_b, nq);
    rungemm<32, 32, 16, false, false>(stream, nq, me_w1, me_b1, nullptr,
                                      nullptr, mea, 800, DD, DD, DD, DD, DD,
                                      1, 1, 1, 0,0,0, 0,0,0, 0,0,0, 0, 1.f, 1);
    rungemm<32, 32, 16, false, false>(stream, mea, me_w2, me_b2, nullptr,
                                      nullptr, meb, 800, DD, DD, DD, DD, DD,
                                      1, 1, 1, 0,0,0, 0,0,0, 0,0,0, 0, 1.f, 1);
    rungemm<32, 32, 16, false, false>(stream, meb, me_w3, me_b3, nullptr,
                                      nullptr, mec, 800, DD, DD, DD, DD, DD,
                                      1, 1, 1, 0,0,0, 0,0,0, 0,0,0, 0, 1.f, 0);
    float* pl = (i < 8) ? (out2 + (size_t)i * BB * QQ * NCC) : out0;
    rungemm<32, 32, 16, false, false>(stream, nq, cls_w, cls_b, nullptr,
                                      nullptr, pl, 800, NCC, DD, DD, DD, NCC,
                                      1, 1, 1, 0,0,0, 0,0,0, 0,0,0, 0, 1.f, 0);
    // mask logits: per-b: mec[100,256] x mfeat[b][256,12544]^T -> pm
    float* pmOut = (i < 8) ? (out3 + (size_t)i * BB * QQ * PP) : out1;
    rungemm<128, 64, 16, false, true>(stream, mec, mfeat, nullptr, nullptr,
        nullptr, pmOut, QQ, PP, DD, DD, PP, PP,
        BB, 1, 1, (long)QQ * DD, 0, 0, (long)DD * PP, 0, 0,
        (long)QQ * PP, 0, 0, 0, 1.f, 0);
    prevPm = pmOut;
  }
}